// Round 4
// baseline (451.253 us; speedup 1.0000x reference)
//
#include <hip/hip_runtime.h>
#include <hip/hip_bf16.h>
#include <math.h>

// Problem constants
#define S 2048
#define H 1024
#define NE 8
#define INTER 2048
#define ALPHA 1.702f
#define LIMIT 7.0f

// Upper bound on total 128-row m-tiles across experts:
// sum_e ceil(cnt_e/128) <= 8 + 4096/128 = 40
#define MAXT 40

typedef __bf16 bf16x8 __attribute__((ext_vector_type(8)));
typedef float f32x4 __attribute__((ext_vector_type(4)));
typedef unsigned short u16x8 __attribute__((ext_vector_type(8)));

// Workspace layout (bytes)
#define WS_COUNTS 0                                   // 4 KB
#define WS_SLOTS  4096                                // int[NE][S] = 64 KB
#define WS_W      (WS_SLOTS + NE*S*4)                 // float[2S] = 16 KB
#define WS_XB     (WS_W + 2*S*4)                      // bf16 x [S][H] = 4 MB
#define WS_GUP    (WS_XB + (size_t)S*H*2)             // bf16 [E][2][I][H] = 64 MB
#define WS_DPN    (WS_GUP + (size_t)NE*2*INTER*H*2)   // bf16 [E][H][I] = 32 MB
#define WS_ACT    (WS_DPN + (size_t)NE*H*INTER*2)     // bf16 [2S][I] = 16 MB

static __device__ __forceinline__ unsigned short f2bf(float f) {
    union { __hip_bfloat16 h; unsigned short u; } cv;
    cv.h = __float2bfloat16(f);
    return cv.u;
}

static __device__ __forceinline__ void gload16(const void* g, void* l) {
    __builtin_amdgcn_global_load_lds(
        (const __attribute__((address_space(1))) unsigned int*)(unsigned long long)g,
        (__attribute__((address_space(3))) unsigned int*)(unsigned int)(unsigned long long)l,
        16, 0, 0);
}

// Decode compact tile index y -> (expert, m0). Returns 0 if y beyond the
// active tile list. Uniform per block (y is blockIdx), ~8 scalar iterations.
static __device__ __forceinline__ int find_tile(const int* __restrict__ counts,
                                                int y, int* e_out, int* m0_out) {
    int base = 0;
#pragma unroll
    for (int e = 0; e < NE; ++e) {
        int nt = (counts[e] + 127) >> 7;
        if (y < base + nt) { *e_out = e; *m0_out = (y - base) << 7; return 1; }
        base += nt;
    }
    return 0;
}

// ---------------------------------------------------------------------------
// Router + x->bf16 conversion. One wave per token.
// ---------------------------------------------------------------------------
__global__ __launch_bounds__(64) void router_conv(
    const float* __restrict__ x, const float* __restrict__ rw,
    const float* __restrict__ rb, int* __restrict__ counts,
    int* __restrict__ slots, float* __restrict__ slot_w,
    unsigned short* __restrict__ xb)
{
    int tok = blockIdx.x;
    int lane = threadIdx.x;
    const float4* xr = (const float4*)(x + (size_t)tok * H);
    ushort4* xo = (ushort4*)(xb + (size_t)tok * H);
    float acc[NE];
#pragma unroll
    for (int e = 0; e < NE; ++e) acc[e] = 0.f;
#pragma unroll
    for (int p = 0; p < H / 256; ++p) {
        int idx = p * 64 + lane;
        float4 v = xr[idx];
        ushort4 o;
        o.x = f2bf(v.x); o.y = f2bf(v.y); o.z = f2bf(v.z); o.w = f2bf(v.w);
        xo[idx] = o;
        const float* wr = rw + (size_t)idx * 4 * NE;
#pragma unroll
        for (int e = 0; e < NE; ++e)
            acc[e] += v.x * wr[e] + v.y * wr[NE + e] + v.z * wr[2 * NE + e] + v.w * wr[3 * NE + e];
    }
#pragma unroll
    for (int e = 0; e < NE; ++e) {
#pragma unroll
        for (int off = 32; off > 0; off >>= 1)
            acc[e] += __shfl_down(acc[e], off);
    }
    if (lane == 0) {
        float v[NE];
#pragma unroll
        for (int e = 0; e < NE; ++e) v[e] = acc[e] + rb[e];
        int i1 = 0; float v1 = v[0];
#pragma unroll
        for (int e = 1; e < NE; ++e) if (v[e] > v1) { v1 = v[e]; i1 = e; }
        int i2 = -1; float v2 = -3.0e38f;
#pragma unroll
        for (int e = 0; e < NE; ++e) if (e != i1 && v[e] > v2) { v2 = v[e]; i2 = e; }
        float w1 = 1.f / (1.f + expf(v2 - v1));
        float w2 = 1.f - w1;
        int p1 = atomicAdd(&counts[i1], 1);
        slots[i1 * S + p1] = tok * 2;
        slot_w[tok * 2] = w1;
        int p2 = atomicAdd(&counts[i2], 1);
        slots[i2 * S + p2] = tok * 2 + 1;
        slot_w[tok * 2 + 1] = w2;
    }
}

// ---------------------------------------------------------------------------
// Weight prep: fp32 [K][N] -> bf16 [N][K]. Conflict-free LDS transpose:
// tile stride 66 u16 (33 dwords, odd) -> write phase 2 lanes/bank (free),
// read phase 16 banks with same-dword broadcast (free).
// Reads: float4 coalesced. Writes: u16x8, 8 lanes = 128B contiguous segment.
// grid: (K/64 * N/64, NE*3)
// ---------------------------------------------------------------------------
__global__ __launch_bounds__(256) void prep(
    const float* __restrict__ gup, const float* __restrict__ dp,
    unsigned short* __restrict__ gw, unsigned short* __restrict__ dw)
{
    int z = blockIdx.y;
    int e = z / 3, which = z % 3;
    const float* in;
    unsigned short* out;
    int K, N, istride;
    if (which == 0) {
        in = gup + (size_t)e * H * 2 * INTER;
        out = gw + (size_t)e * 2 * INTER * H;
        K = H; N = INTER; istride = 2 * INTER;
    } else if (which == 1) {
        in = gup + (size_t)e * H * 2 * INTER + INTER;
        out = gw + (size_t)e * 2 * INTER * H + (size_t)INTER * H;
        K = H; N = INTER; istride = 2 * INTER;
    } else {
        in = dp + (size_t)e * INTER * H;
        out = dw + (size_t)e * H * INTER;
        K = INTER; N = H; istride = H;
    }
    int ntiles = N / 64;
    int k0 = (blockIdx.x / ntiles) * 64;
    int n0 = (blockIdx.x % ntiles) * 64;

    __shared__ unsigned short tile[64][66];
    int t = threadIdx.x;
    int lk = t >> 4, ln = (t & 15) * 4;
#pragma unroll
    for (int p = 0; p < 4; ++p) {
        int kk = lk + p * 16;
        float4 v = *(const float4*)(in + (size_t)(k0 + kk) * istride + n0 + ln);
        tile[kk][ln + 0] = f2bf(v.x); tile[kk][ln + 1] = f2bf(v.y);
        tile[kk][ln + 2] = f2bf(v.z); tile[kk][ln + 3] = f2bf(v.w);
    }
    __syncthreads();
    int wn = t >> 3, wk = (t & 7) * 8;
#pragma unroll
    for (int q = 0; q < 2; ++q) {
        int nn = wn + q * 32;
        u16x8 o;
#pragma unroll
        for (int i = 0; i < 8; ++i) o[i] = tile[wk + i][nn];
        *(u16x8*)(out + (size_t)(n0 + nn) * K + k0 + wk) = o;
    }
}

// ---------------------------------------------------------------------------
// Grouped gate_up MFMA GEMM + fused activation -> act (bf16).
// Compact grid: y indexes active (expert, m-tile) pairs via find_tile.
// Tile M=128 x N=64 (gate+up together), BK=32, 4 waves 2x2.
// ---------------------------------------------------------------------------
__global__ __launch_bounds__(256) void gateup_mfma(
    const unsigned short* __restrict__ xb,
    const unsigned short* __restrict__ gw,
    const float* __restrict__ gub,
    const int* __restrict__ counts, const int* __restrict__ slots,
    unsigned short* __restrict__ act)
{
    int e, m0;
    if (!find_tile(counts, blockIdx.y, &e, &m0)) return;
    int cnt = counts[e];
    int n0 = blockIdx.x * 64;

    __shared__ unsigned short As[128 * 32];
    __shared__ unsigned short Gs[64 * 32];
    __shared__ unsigned short Us[64 * 32];
    __shared__ int sl[128];

    int t = threadIdx.x;
    int lane = t & 63, w = t >> 6;
    if (t < 128) {
        int r = m0 + t;
        sl[t] = slots[e * S + (r < cnt ? r : cnt - 1)];
    }
    __syncthreads();

    int quad = lane >> 4, l16 = lane & 15;
    int wm = (w >> 1) * 64, wn = (w & 1) * 32;

    int ar0 = w * 32 + (lane >> 2);
    int ar1 = ar0 + 16;
    const unsigned short* ap0 = xb + (size_t)(sl[ar0] >> 1) * H + (lane & 3) * 8;
    const unsigned short* ap1 = xb + (size_t)(sl[ar1] >> 1) * H + (lane & 3) * 8;
    int bn = w * 16 + (lane >> 2);
    const unsigned short* gp = gw + (size_t)e * 2 * INTER * H + (size_t)(n0 + bn) * H + (lane & 3) * 8;
    const unsigned short* up = gp + (size_t)INTER * H;

    unsigned short* la0 = &As[(2 * w) * 512 + lane * 8];
    unsigned short* la1 = &As[(2 * w + 1) * 512 + lane * 8];
    unsigned short* lg = &Gs[w * 512 + lane * 8];
    unsigned short* lu = &Us[w * 512 + lane * 8];

    f32x4 accg[4][2], accu[4][2];
#pragma unroll
    for (int mi = 0; mi < 4; ++mi)
#pragma unroll
        for (int ni = 0; ni < 2; ++ni) {
            accg[mi][ni] = (f32x4){0.f, 0.f, 0.f, 0.f};
            accu[mi][ni] = (f32x4){0.f, 0.f, 0.f, 0.f};
        }

    for (int k0 = 0; k0 < H; k0 += 32) {
        __syncthreads();
        gload16(ap0 + k0, la0);
        gload16(ap1 + k0, la1);
        gload16(gp + k0, lg);
        gload16(up + k0, lu);
        __syncthreads();
        bf16x8 af[4], gf[2], uf[2];
#pragma unroll
        for (int mi = 0; mi < 4; ++mi)
            af[mi] = *(const bf16x8*)&As[(wm + mi * 16 + l16) * 32 + quad * 8];
#pragma unroll
        for (int ni = 0; ni < 2; ++ni) {
            gf[ni] = *(const bf16x8*)&Gs[(wn + ni * 16 + l16) * 32 + quad * 8];
            uf[ni] = *(const bf16x8*)&Us[(wn + ni * 16 + l16) * 32 + quad * 8];
        }
#pragma unroll
        for (int mi = 0; mi < 4; ++mi)
#pragma unroll
            for (int ni = 0; ni < 2; ++ni) {
                accg[mi][ni] = __builtin_amdgcn_mfma_f32_16x16x32_bf16(af[mi], gf[ni], accg[mi][ni], 0, 0, 0);
                accu[mi][ni] = __builtin_amdgcn_mfma_f32_16x16x32_bf16(af[mi], uf[ni], accu[mi][ni], 0, 0, 0);
            }
    }

    const float* gb = gub + (size_t)e * 2 * INTER;
#pragma unroll
    for (int mi = 0; mi < 4; ++mi) {
#pragma unroll
        for (int r = 0; r < 4; ++r) {
            int rt = wm + mi * 16 + quad * 4 + r;
            if (m0 + rt >= cnt) continue;
            int slot = sl[rt];
            unsigned short* orow = act + (size_t)slot * INTER;
#pragma unroll
            for (int ni = 0; ni < 2; ++ni) {
                int col = n0 + wn + ni * 16 + l16;
                float gate = accg[mi][ni][r] + gb[col];
                float uv = accu[mi][ni][r] + gb[INTER + col];
                gate = fminf(gate, LIMIT);
                uv = fminf(fmaxf(uv, -LIMIT), LIMIT);
                float glu = gate / (1.f + __expf(-ALPHA * gate));
                orow[col] = f2bf((uv + 1.f) * glu);
            }
        }
    }
}

// ---------------------------------------------------------------------------
// Grouped down MFMA GEMM + bias + weighted combine. Compact grid in y,
// K-split 2 in z; partials atomicAdd (bias added by ks==0 only).
// ---------------------------------------------------------------------------
__global__ __launch_bounds__(256) void down_mfma(
    const unsigned short* __restrict__ act,
    const unsigned short* __restrict__ dw,
    const float* __restrict__ db,
    const int* __restrict__ counts, const int* __restrict__ slots,
    const float* __restrict__ slot_w,
    float* __restrict__ out)
{
    int e, m0;
    if (!find_tile(counts, blockIdx.y, &e, &m0)) return;
    int ks = blockIdx.z;
    int cnt = counts[e];
    int n0 = blockIdx.x * 64;

    __shared__ unsigned short As[128 * 32];
    __shared__ unsigned short Bs[64 * 32];
    __shared__ int sl[128];

    int t = threadIdx.x;
    int lane = t & 63, w = t >> 6;
    if (t < 128) {
        int r = m0 + t;
        sl[t] = slots[e * S + (r < cnt ? r : cnt - 1)];
    }
    __syncthreads();

    int quad = lane >> 4, l16 = lane & 15;
    int wm = (w >> 1) * 64, wn = (w & 1) * 32;

    int ar0 = w * 32 + (lane >> 2);
    int ar1 = ar0 + 16;
    int kbase = ks * (INTER / 2);
    const unsigned short* ap0 = act + (size_t)sl[ar0] * INTER + kbase + (lane & 3) * 8;
    const unsigned short* ap1 = act + (size_t)sl[ar1] * INTER + kbase + (lane & 3) * 8;
    int bn = w * 16 + (lane >> 2);
    const unsigned short* bp = dw + (size_t)e * H * INTER + (size_t)(n0 + bn) * INTER + kbase + (lane & 3) * 8;

    unsigned short* la0 = &As[(2 * w) * 512 + lane * 8];
    unsigned short* la1 = &As[(2 * w + 1) * 512 + lane * 8];
    unsigned short* lb = &Bs[w * 512 + lane * 8];

    f32x4 acc[4][2];
#pragma unroll
    for (int mi = 0; mi < 4; ++mi)
#pragma unroll
        for (int ni = 0; ni < 2; ++ni)
            acc[mi][ni] = (f32x4){0.f, 0.f, 0.f, 0.f};

    for (int k0 = 0; k0 < INTER / 2; k0 += 32) {
        __syncthreads();
        gload16(ap0 + k0, la0);
        gload16(ap1 + k0, la1);
        gload16(bp + k0, lb);
        __syncthreads();
        bf16x8 af[4], bf[2];
#pragma unroll
        for (int mi = 0; mi < 4; ++mi)
            af[mi] = *(const bf16x8*)&As[(wm + mi * 16 + l16) * 32 + quad * 8];
#pragma unroll
        for (int ni = 0; ni < 2; ++ni)
            bf[ni] = *(const bf16x8*)&Bs[(wn + ni * 16 + l16) * 32 + quad * 8];
#pragma unroll
        for (int mi = 0; mi < 4; ++mi)
#pragma unroll
            for (int ni = 0; ni < 2; ++ni)
                acc[mi][ni] = __builtin_amdgcn_mfma_f32_16x16x32_bf16(af[mi], bf[ni], acc[mi][ni], 0, 0, 0);
    }

    const float* dbr = db + (size_t)e * H;
#pragma unroll
    for (int mi = 0; mi < 4; ++mi) {
#pragma unroll
        for (int r = 0; r < 4; ++r) {
            int rt = wm + mi * 16 + quad * 4 + r;
            if (m0 + rt >= cnt) continue;
            int slot = sl[rt];
            int tok = slot >> 1;
            float wgt = slot_w[slot];
#pragma unroll
            for (int ni = 0; ni < 2; ++ni) {
                int col = n0 + wn + ni * 16 + l16;
                float rr = acc[mi][ni][r] + (ks == 0 ? dbr[col] : 0.f);
                atomicAdd(&out[(size_t)tok * H + col], wgt * rr);
            }
        }
    }
}

// ---------------------------------------------------------------------------
extern "C" void kernel_launch(void* const* d_in, const int* in_sizes, int n_in,
                              void* d_out, int out_size, void* d_ws, size_t ws_size,
                              hipStream_t stream)
{
    const float* x   = (const float*)d_in[0];
    const float* rw  = (const float*)d_in[1];
    const float* rb  = (const float*)d_in[2];
    const float* gup = (const float*)d_in[3];
    const float* gub = (const float*)d_in[4];
    const float* dp  = (const float*)d_in[5];
    const float* db  = (const float*)d_in[6];
    float* out = (float*)d_out;

    char* ws = (char*)d_ws;
    int* counts            = (int*)(ws + WS_COUNTS);
    int* slots             = (int*)(ws + WS_SLOTS);
    float* slot_w          = (float*)(ws + WS_W);
    unsigned short* xb     = (unsigned short*)(ws + WS_XB);
    unsigned short* gw     = (unsigned short*)(ws + WS_GUP);
    unsigned short* dw     = (unsigned short*)(ws + WS_DPN);
    unsigned short* act    = (unsigned short*)(ws + WS_ACT);

    hipMemsetAsync(counts, 0, 4096, stream);
    hipMemsetAsync(out, 0, (size_t)S * H * sizeof(float), stream);

    router_conv<<<S, 64, 0, stream>>>(x, rw, rb, counts, slots, slot_w, xb);

    prep<<<dim3(512, NE * 3), 256, 0, stream>>>(gup, dp, gw, dw);

    gateup_mfma<<<dim3(INTER / 64, MAXT), 256, 0, stream>>>(
        xb, gw, gub, counts, slots, act);

    down_mfma<<<dim3(H / 64, MAXT, 2), 256, 0, stream>>>(
        act, dw, db, counts, slots, slot_w, out);
}